// Round 5
// baseline (473.430 us; speedup 1.0000x reference)
//
#include <hip/hip_runtime.h>

typedef __attribute__((ext_vector_type(8))) short short8;
typedef __attribute__((ext_vector_type(4))) float floatx4;

constexpr int Bb = 2, Ss = 2048, Dd = 1024, Hh = 16, Pp = 128, DHh = 64;
constexpr int NS = Ss + Pp; // 2176

#define DEVI __device__ __forceinline__

// LDS-visibility sync: drain own LDS ops, then barrier. Does NOT drain vmcnt
// (global stores / in-flight loads keep flowing across tiles).
#define SYNC_LDS()                                          \
  do {                                                      \
    asm volatile("s_waitcnt lgkmcnt(0)" ::: "memory");      \
    __builtin_amdgcn_s_barrier();                           \
  } while (0)
// For global_load_lds staging: vmcnt tracks LDS-DMA completion.
#define SYNC_VM()                                           \
  do {                                                      \
    asm volatile("s_waitcnt vmcnt(0)" ::: "memory");        \
    __builtin_amdgcn_s_barrier();                           \
  } while (0)

DEVI unsigned short f2bf(float f) {
  unsigned u = __float_as_uint(f);
  u += 0x7fffu + ((u >> 16) & 1u);
  return (unsigned short)(u >> 16);
}
DEVI float bf2f(unsigned short h) { return __uint_as_float(((unsigned)h) << 16); }

DEVI void gl_lds16(const unsigned short* g, unsigned short* l) {
  __builtin_amdgcn_global_load_lds((const __attribute__((address_space(1))) unsigned int*)g,
                                   (__attribute__((address_space(3))) unsigned int*)l, 16, 0, 0);
}

// ---------------- weight transpose + f32->bf16 ----------------
__global__ __launch_bounds__(256) void wt_cvt_kernel(const float* __restrict__ W,
                                                     unsigned short* __restrict__ Wt,
                                                     int K, int N) {
  __shared__ float t[32][33];
  int n0 = blockIdx.x * 32, k0 = blockIdx.y * 32;
  int tx = threadIdx.x & 31, ty = threadIdx.x >> 5;
#pragma unroll
  for (int j = 0; j < 4; j++)
    t[ty + 8 * j][tx] = W[(long)(k0 + ty + 8 * j) * N + n0 + tx];
  __syncthreads();
#pragma unroll
  for (int j = 0; j < 4; j++)
    Wt[(long)(n0 + ty + 8 * j) * K + k0 + tx] = f2bf(t[tx][ty + 8 * j]);
}

// ---------------- layernorm ----------------
__global__ __launch_bounds__(256) void ln_kernel(const float* __restrict__ x,
                                                 const float* __restrict__ g,
                                                 const float* __restrict__ bia,
                                                 unsigned short* __restrict__ out) {
  int row = blockIdx.x;
  int t = threadIdx.x;
  const float4* xr = (const float4*)(x + (long)row * Dd);
  float4 v = xr[t];
  float s1 = v.x + v.y + v.z + v.w;
  float s2 = v.x * v.x + v.y * v.y + v.z * v.z + v.w * v.w;
#pragma unroll
  for (int o = 1; o < 64; o <<= 1) {
    s1 += __shfl_xor(s1, o);
    s2 += __shfl_xor(s2, o);
  }
  __shared__ float r1[4], r2[4];
  int wid = t >> 6;
  if ((t & 63) == 0) { r1[wid] = s1; r2[wid] = s2; }
  __syncthreads();
  s1 = r1[0] + r1[1] + r1[2] + r1[3];
  s2 = r2[0] + r2[1] + r2[2] + r2[3];
  float mean = s1 * (1.0f / Dd);
  float var = s2 * (1.0f / Dd) - mean * mean;
  float rstd = rsqrtf(var + 1e-3f);
  float4 gg = ((const float4*)g)[t];
  float4 bb = ((const float4*)bia)[t];
  ushort4 o;
  o.x = f2bf((v.x - mean) * rstd * gg.x + bb.x);
  o.y = f2bf((v.y - mean) * rstd * gg.y + bb.y);
  o.z = f2bf((v.z - mean) * rstd * gg.z + bb.z);
  o.w = f2bf((v.w - mean) * rstd * gg.w + bb.w);
  *((ushort4*)(out + (long)row * Dd + t * 4)) = o;
}

// ---------------- past rows -> kcat/vcat head-layout ----------------
__global__ __launch_bounds__(256) void past_fill_kernel(const float* __restrict__ past,
                                                        unsigned short* __restrict__ kc_,
                                                        unsigned short* __restrict__ vc_) {
  long idx = (long)blockIdx.x * 256 + threadIdx.x; // b(2) h(16) p(128) dh(64)
  int dh = idx & 63;
  int p = (int)((idx >> 6) & 127);
  int h = (int)((idx >> 13) & 15);
  int b = (int)(idx >> 17);
  long bh = (long)b * Hh + h;
  float pk = past[((((long)b * 2 + 0) * Hh + h) * Pp + p) * DHh + dh];
  float pv = past[((((long)b * 2 + 1) * Hh + h) * Pp + p) * DHh + dh];
  kc_[(bh * NS + p) * DHh + dh] = f2bf(pk);
  vc_[(bh * NS + p) * DHh + dh] = f2bf(pv);
}

// ---------------- V transpose: (z, NS, 64) -> (z, 64, NS) ----------------
__global__ __launch_bounds__(256) void vtr_kernel(const unsigned short* __restrict__ vcat,
                                                  unsigned short* __restrict__ vT) {
  __shared__ unsigned short Tl[64 * 72];
  int z = blockIdx.y;
  int s0 = blockIdx.x * 64;
  int t = threadIdx.x;
#pragma unroll
  for (int it = 0; it < 2; it++) {
    int idx = t + it * 256, row = idx >> 3, c8 = (idx & 7) * 8;
    *(short8*)&Tl[row * 72 + c8] = *(const short8*)(vcat + ((long)z * NS + s0 + row) * 64 + c8);
  }
  __syncthreads();
#pragma unroll
  for (int it = 0; it < 2; it++) {
    int idx = t + it * 256, row = idx >> 3, c8 = (idx & 7) * 8;
    short8 g;
#pragma unroll
    for (int e = 0; e < 8; e++) g[e] = (short)Tl[(c8 + e) * 72 + row];
    *(short8*)(vT + ((long)z * 64 + row) * NS + s0 + c8) = g;
  }
}

// ---------------- fused attention ----------------
__global__ __launch_bounds__(256) void attn_kernel(const unsigned short* __restrict__ qg,
                                                   const unsigned short* __restrict__ kcat,
                                                   const unsigned short* __restrict__ vTg,
                                                   float* __restrict__ wg,
                                                   unsigned short* __restrict__ am) {
  __shared__ unsigned short KV[128 * 72];
  __shared__ unsigned short Pl[128 * 136];
  int wgs = (blockIdx.x & 7) * 64 + (blockIdx.x >> 3);
  int z = wgs >> 4;
  int bx = 15 - (wgs & 15);
  int q0 = bx * 128;
  int t = threadIdx.x, lane = t & 63, wid = t >> 6;
  int lr = lane & 15, kgp = lane >> 4;
  const unsigned short* qz = qg + (long)z * Ss * 64;
  const unsigned short* kz = kcat + (long)z * NS * 64;
  const unsigned short* vz = vTg + (long)z * 64 * NS;
  float* wz = wg + (long)z * Ss * NS;

  short8 qa[2][2];
#pragma unroll
  for (int i = 0; i < 2; i++)
#pragma unroll
    for (int kk = 0; kk < 2; kk++)
      qa[i][kk] =
          *(const short8*)(qz + (long)(q0 + wid * 32 + i * 16 + lr) * 64 + kk * 32 + kgp * 8);

  const int nt = bx + 2;
  float l_run[2][4] = {};

  // ---- pass 1: denominators (fixed max M0=8) ----
  for (int kt = 0; kt < nt; kt++) {
#pragma unroll
    for (int it = 0; it < 4; it++) {
      int idx = t + it * 256, row = idx >> 3, c8 = (idx & 7) * 8;
      *(short8*)&KV[row * 72 + c8] = *(const short8*)(kz + (long)(kt * 128 + row) * 64 + c8);
    }
    SYNC_LDS();
    floatx4 acc[2][8] = {};
    __builtin_amdgcn_s_setprio(1);
#pragma unroll
    for (int j = 0; j < 8; j++) {
      short8 b0 = *(const short8*)&KV[(j * 16 + lr) * 72 + kgp * 8];
      short8 b1 = *(const short8*)&KV[(j * 16 + lr) * 72 + 32 + kgp * 8];
#pragma unroll
      for (int i = 0; i < 2; i++) {
        acc[i][j] = __builtin_amdgcn_mfma_f32_16x16x32_bf16(qa[i][0], b0, acc[i][j], 0, 0, 0);
        acc[i][j] = __builtin_amdgcn_mfma_f32_16x16x32_bf16(qa[i][1], b1, acc[i][j], 0, 0, 0);
      }
    }
    __builtin_amdgcn_s_setprio(0);
#pragma unroll
    for (int i = 0; i < 2; i++) {
#pragma unroll
      for (int r = 0; r < 4; r++) {
        int row = q0 + wid * 32 + i * 16 + kgp * 4 + r;
        float su = 0.f;
#pragma unroll
        for (int j = 0; j < 8; j++) {
          int col = kt * 128 + j * 16 + lr;
          float e = (col > row + Pp) ? 0.f : __expf(acc[i][j][r] * 0.125f - 8.0f);
          su += e;
        }
        su += __shfl_xor(su, 1);
        su += __shfl_xor(su, 2);
        su += __shfl_xor(su, 4);
        su += __shfl_xor(su, 8);
        l_run[i][r] += su;
      }
    }
    SYNC_LDS(); // readers done before next tile's staging overwrites KV
  }

  float cc[2][4];
#pragma unroll
  for (int i = 0; i < 2; i++)
#pragma unroll
    for (int r = 0; r < 4; r++) cc[i][r] = 8.0f + __logf(l_run[i][r]);

  // ---- pass 2: w + PV ----
  floatx4 oacc[2][4] = {};
  for (int kt = 0; kt < nt; kt++) {
#pragma unroll
    for (int it = 0; it < 4; it++) {
      int idx = t + it * 256, row = idx >> 3, c8 = (idx & 7) * 8;
      *(short8*)&KV[row * 72 + c8] = *(const short8*)(kz + (long)(kt * 128 + row) * 64 + c8);
    }
    SYNC_LDS();
    floatx4 acc[2][8] = {};
    __builtin_amdgcn_s_setprio(1);
#pragma unroll
    for (int j = 0; j < 8; j++) {
      short8 b0 = *(const short8*)&KV[(j * 16 + lr) * 72 + kgp * 8];
      short8 b1 = *(const short8*)&KV[(j * 16 + lr) * 72 + 32 + kgp * 8];
#pragma unroll
      for (int i = 0; i < 2; i++) {
        acc[i][j] = __builtin_amdgcn_mfma_f32_16x16x32_bf16(qa[i][0], b0, acc[i][j], 0, 0, 0);
        acc[i][j] = __builtin_amdgcn_mfma_f32_16x16x32_bf16(qa[i][1], b1, acc[i][j], 0, 0, 0);
      }
    }
    __builtin_amdgcn_s_setprio(0);
#pragma unroll
    for (int i = 0; i < 2; i++) {
#pragma unroll
      for (int r = 0; r < 4; r++) {
        int row = q0 + wid * 32 + i * 16 + kgp * 4 + r;
#pragma unroll
        for (int j = 0; j < 8; j++) {
          int col = kt * 128 + j * 16 + lr;
          float p = (col > row + Pp) ? 0.f : __expf(acc[i][j][r] * 0.125f - cc[i][r]);
          wz[(long)row * NS + col] = p;
          Pl[(wid * 32 + i * 16 + kgp * 4 + r) * 136 + j * 16 + lr] = f2bf(p);
        }
      }
    }
    SYNC_LDS(); // K readers done + Pl visible
#pragma unroll
    for (int it = 0; it < 4; it++) {
      int idx = t + it * 256, row = idx >> 4, c8 = (idx & 15) * 8;
      *(short8*)&KV[row * 136 + c8] = *(const short8*)(vz + (long)row * NS + kt * 128 + c8);
    }
    SYNC_LDS(); // V staged
    __builtin_amdgcn_s_setprio(1);
#pragma unroll
    for (int kk = 0; kk < 4; kk++) {
      short8 pa[2];
#pragma unroll
      for (int i = 0; i < 2; i++)
        pa[i] = *(const short8*)&Pl[(wid * 32 + i * 16 + lr) * 136 + kk * 32 + kgp * 8];
#pragma unroll
      for (int jd = 0; jd < 4; jd++) {
        short8 bv = *(const short8*)&KV[(jd * 16 + lr) * 136 + kk * 32 + kgp * 8];
#pragma unroll
        for (int i = 0; i < 2; i++)
          oacc[i][jd] = __builtin_amdgcn_mfma_f32_16x16x32_bf16(pa[i], bv, oacc[i][jd], 0, 0, 0);
      }
    }
    __builtin_amdgcn_s_setprio(0);
    SYNC_LDS(); // PV readers done before next K staging
  }

  int zc0 = nt * 128;
  if (zc0 < NS) {
    for (int rr = 0; rr < 32; rr++) {
      int row = q0 + wid * 32 + rr;
      for (int c = zc0 + (lane << 2); c < NS; c += 256) {
        float4 z4 = {0.f, 0.f, 0.f, 0.f};
        *(float4*)&wz[(long)row * NS + c] = z4;
      }
    }
  }

#pragma unroll
  for (int i = 0; i < 2; i++)
#pragma unroll
    for (int jd = 0; jd < 4; jd++)
#pragma unroll
      for (int r = 0; r < 4; r++) {
        long row = (long)(z >> 4) * Ss + q0 + wid * 32 + i * 16 + kgp * 4 + r;
        int col = (z & 15) * 64 + jd * 16 + lr;
        am[row * Dd + col] = f2bf(oacc[i][jd][r]);
      }
}

// ---------------- bf16 MFMA GEMM (m97 structure) + grouped XCD swizzle ----------------
enum { EPI_QKV = 0, EPI_RES = 3, EPI_GELU = 4 };

template <int EPI, int NB>
__global__ __launch_bounds__(256) void gemm_k(const unsigned short* __restrict__ A16,
                                              const unsigned short* __restrict__ Bt,
                                              const float* __restrict__ bias,
                                              const float* __restrict__ res,
                                              void* __restrict__ outv,
                                              unsigned short* __restrict__ kout,
                                              unsigned short* __restrict__ vout,
                                              float* __restrict__ present,
                                              int M, int N, int K, int nwg) {
  constexpr int BM = 128, BN = 128;
  __shared__ unsigned short Alds[BM * 32];
  __shared__ unsigned short Blds[BN * 32];
  int cpx = nwg >> 3;
  int wgid = (blockIdx.x & 7) * cpx + (blockIdx.x >> 3);
  int mb = wgid / NB, nb = wgid % NB;
  int m0 = mb * BM, n0 = nb * BN;
  int t = threadIdx.x;
  int lane = t & 63, wid = t >> 6;
  int wm = wid >> 1, wn = wid & 1;
  floatx4 acc[4][4] = {};
  int lr = lane & 15, kg = lane >> 4;

  const unsigned short* Ab = A16 + (long)(m0 + wid * 32 + (lane >> 2)) * K + (lane & 3) * 8;
  const unsigned short* Bp = Bt + (long)(n0 + wid * 32 + (lane >> 2)) * K + (lane & 3) * 8;
  unsigned short* AL0 = &Alds[(wid * 32) * 32];
  unsigned short* AL1 = &Alds[(wid * 32 + 16) * 32];
  unsigned short* BL0 = &Blds[(wid * 32) * 32];
  unsigned short* BL1 = &Blds[(wid * 32 + 16) * 32];
  long rstride = (long)16 * K;

  for (int k0 = 0; k0 < K; k0 += 32) {
    gl_lds16(Ab + k0, AL0);
    gl_lds16(Ab + rstride + k0, AL1);
    gl_lds16(Bp + k0, BL0);
    gl_lds16(Bp + rstride + k0, BL1);
    SYNC_VM(); // staging complete (vmcnt tracks LDS-DMA)
    short8 a[4], b[4];
#pragma unroll
    for (int i = 0; i < 4; i++)
      a[i] = *(const short8*)&Alds[(wm * 64 + i * 16 + lr) * 32 + kg * 8];
#pragma unroll
    for (int j = 0; j < 4; j++)
      b[j] = *(const short8*)&Blds[(wn * 64 + j * 16 + lr) * 32 + kg * 8];
#pragma unroll
    for (int i = 0; i < 4; i++)
#pragma unroll
      for (int j = 0; j < 4; j++)
        acc[i][j] = __builtin_amdgcn_mfma_f32_16x16x32_bf16(a[i], b[j], acc[i][j], 0, 0, 0);
    SYNC_LDS(); // readers done before next stage overwrites
  }

#pragma unroll
  for (int i = 0; i < 4; i++) {
#pragma unroll
    for (int j = 0; j < 4; j++) {
#pragma unroll
      for (int r = 0; r < 4; r++) {
        int mm = m0 + wm * 64 + i * 16 + kg * 4 + r;
        int nn = n0 + wn * 64 + j * 16 + lr;
        float v = acc[i][j][r];
        if constexpr (EPI == EPI_QKV) {
          // fused bias + head-split + present emission
          float vv = v + bias[nn];
          int b = mm >> 11, s = mm & 2047;
          int sec = nn >> 10, hd = nn & 1023;
          int hh = hd >> 6, dh = hd & 63;
          long bh = (long)b * Hh + hh;
          if (sec == 0) {
            ((unsigned short*)outv)[(bh * Ss + s) * DHh + dh] = f2bf(vv); // q
          } else {
            unsigned short* dst = (sec == 1) ? kout : vout;
            dst[(bh * NS + Pp + s) * DHh + dh] = f2bf(vv);
            present[((((long)b * 2 + (sec - 1)) * Hh + hh) * Ss + s) * DHh + dh] = vv;
          }
        } else if constexpr (EPI == EPI_RES) {
          ((float*)outv)[(long)mm * N + nn] = v + bias[nn] + res[(long)mm * N + nn];
        } else if constexpr (EPI == EPI_GELU) {
          float xv = v + bias[nn];
          float u = xv + 0.044715f * xv * xv * xv;
          float tv = 1.0f - 2.0f / (__expf(1.5957691216057308f * u) + 1.0f);
          ((unsigned short*)outv)[(long)mm * N + nn] = f2bf(0.5f * xv * (1.0f + tv));
        }
      }
    }
  }
}

extern "C" void kernel_launch(void* const* d_in, const int* in_sizes, int n_in,
                              void* d_out, int out_size, void* d_ws, size_t ws_size,
                              hipStream_t stream) {
  (void)in_sizes; (void)n_in; (void)out_size; (void)ws_size;
  const float* x = (const float*)d_in[0];
  const float* past = (const float*)d_in[1];
  const float* qkv_w = (const float*)d_in[2];
  const float* qkv_b = (const float*)d_in[3];
  const float* merge_w = (const float*)d_in[4];
  const float* merge_b = (const float*)d_in[5];
  const float* ln1_w = (const float*)d_in[6];
  const float* ln1_b = (const float*)d_in[7];
  const float* ln2_w = (const float*)d_in[8];
  const float* ln2_b = (const float*)d_in[9];
  const float* g1 = (const float*)d_in[10];
  const float* b1 = (const float*)d_in[11];
  const float* g2 = (const float*)d_in[12];
  const float* b2 = (const float*)d_in[13];

  char* ws = (char*)d_ws;
  unsigned short* qkv_wT = (unsigned short*)(ws + 0);
  unsigned short* merge_wT = (unsigned short*)(ws + 6291456);
  unsigned short* ln1_wT = (unsigned short*)(ws + 8388608);
  unsigned short* ln2_wT = (unsigned short*)(ws + 16777216);
  unsigned short* h = (unsigned short*)(ws + 25165824);
  unsigned short* q = (unsigned short*)(ws + 33554432);
  unsigned short* kcat = (unsigned short*)(ws + 41943040);
  unsigned short* vcat = (unsigned short*)(ws + 50855936);
  unsigned short* am = (unsigned short*)(ws + 59768832);   // 8.4 MB
  unsigned short* vT = (unsigned short*)(ws + 68157440);   // dead before xa written
  unsigned short* m1 = (unsigned short*)(ws + 25165824);   // reuse h..vcat after attn
  float* xa = (float*)(ws + 68157440);
  unsigned short* h2 = (unsigned short*)(ws + 84934656);

  float* xm_out = (float*)d_out;
  float* present = ((float*)d_out) + (long)Bb * Ss * Dd;
  float* w_out = present + (long)Bb * 2 * Hh * Ss * DHh;

  wt_cvt_kernel<<<dim3(3072 / 32, 1024 / 32), 256, 0, stream>>>(qkv_w, qkv_wT, 1024, 3072);
  wt_cvt_kernel<<<dim3(1024 / 32, 1024 / 32), 256, 0, stream>>>(merge_w, merge_wT, 1024, 1024);
  wt_cvt_kernel<<<dim3(4096 / 32, 1024 / 32), 256, 0, stream>>>(ln1_w, ln1_wT, 1024, 4096);
  wt_cvt_kernel<<<dim3(1024 / 32, 4096 / 32), 256, 0, stream>>>(ln2_w, ln2_wT, 4096, 1024);

  ln_kernel<<<Bb * Ss, 256, 0, stream>>>(x, g1, b1, h);

  // QKV GEMM with fused head-split + present
  gemm_k<EPI_QKV, 24><<<32 * 24, 256, 0, stream>>>(
      h, qkv_wT, qkv_b, nullptr, q, kcat, vcat, present, 4096, 3072, 1024, 32 * 24);

  past_fill_kernel<<<(Bb * Hh * Pp * DHh) / 256, 256, 0, stream>>>(past, kcat, vcat);

  vtr_kernel<<<dim3(NS / 64, Bb * Hh), 256, 0, stream>>>(vcat, vT);

  attn_kernel<<<512, 256, 0, stream>>>(q, kcat, vT, w_out, am);

  gemm_k<EPI_RES, 8><<<32 * 8, 256, 0, stream>>>(
      am, merge_wT, merge_b, x, xa, nullptr, nullptr, nullptr, 4096, 1024, 1024, 32 * 8);

  ln_kernel<<<Bb * Ss, 256, 0, stream>>>(xa, g2, b2, h2);

  gemm_k<EPI_GELU, 32><<<32 * 32, 256, 0, stream>>>(
      h2, ln1_wT, ln1_b, nullptr, m1, nullptr, nullptr, nullptr, 4096, 4096, 1024, 32 * 32);

  gemm_k<EPI_RES, 8><<<32 * 8, 256, 0, stream>>>(
      m1, ln2_wT, ln2_b, x, xm_out, nullptr, nullptr, nullptr, 4096, 1024, 4096, 32 * 8);
}

// Round 6
// 451.378 us; speedup vs baseline: 1.0489x; 1.0489x over previous
//
#include <hip/hip_runtime.h>

typedef __attribute__((ext_vector_type(8))) short short8;
typedef __attribute__((ext_vector_type(4))) float floatx4;

constexpr int Bb = 2, Ss = 2048, Dd = 1024, Hh = 16, Pp = 128, DHh = 64;
constexpr int NS = Ss + Pp; // 2176

#define DEVI __device__ __forceinline__

#define SYNC_LDS()                                          \
  do {                                                      \
    asm volatile("s_waitcnt lgkmcnt(0)" ::: "memory");      \
    __builtin_amdgcn_s_barrier();                           \
  } while (0)
#define SYNC_VM()                                           \
  do {                                                      \
    asm volatile("s_waitcnt vmcnt(0)" ::: "memory");        \
    __builtin_amdgcn_s_barrier();                           \
  } while (0)

DEVI unsigned short f2bf(float f) {
  unsigned u = __float_as_uint(f);
  u += 0x7fffu + ((u >> 16) & 1u);
  return (unsigned short)(u >> 16);
}
DEVI float bf2f(unsigned short h) { return __uint_as_float(((unsigned)h) << 16); }

DEVI void gl_lds16(const unsigned short* g, unsigned short* l) {
  __builtin_amdgcn_global_load_lds((const __attribute__((address_space(1))) unsigned int*)g,
                                   (__attribute__((address_space(3))) unsigned int*)l, 16, 0, 0);
}

// ---------------- weight transpose + f32->bf16 ----------------
__global__ __launch_bounds__(256) void wt_cvt_kernel(const float* __restrict__ W,
                                                     unsigned short* __restrict__ Wt,
                                                     int K, int N) {
  __shared__ float t[32][33];
  int n0 = blockIdx.x * 32, k0 = blockIdx.y * 32;
  int tx = threadIdx.x & 31, ty = threadIdx.x >> 5;
#pragma unroll
  for (int j = 0; j < 4; j++)
    t[ty + 8 * j][tx] = W[(long)(k0 + ty + 8 * j) * N + n0 + tx];
  __syncthreads();
#pragma unroll
  for (int j = 0; j < 4; j++)
    Wt[(long)(n0 + ty + 8 * j) * K + k0 + tx] = f2bf(t[tx][ty + 8 * j]);
}

// ---------------- layernorm ----------------
__global__ __launch_bounds__(256) void ln_kernel(const float* __restrict__ x,
                                                 const float* __restrict__ g,
                                                 const float* __restrict__ bia,
                                                 unsigned short* __restrict__ out) {
  int row = blockIdx.x;
  int t = threadIdx.x;
  const float4* xr = (const float4*)(x + (long)row * Dd);
  float4 v = xr[t];
  float s1 = v.x + v.y + v.z + v.w;
  float s2 = v.x * v.x + v.y * v.y + v.z * v.z + v.w * v.w;
#pragma unroll
  for (int o = 1; o < 64; o <<= 1) {
    s1 += __shfl_xor(s1, o);
    s2 += __shfl_xor(s2, o);
  }
  __shared__ float r1[4], r2[4];
  int wid = t >> 6;
  if ((t & 63) == 0) { r1[wid] = s1; r2[wid] = s2; }
  __syncthreads();
  s1 = r1[0] + r1[1] + r1[2] + r1[3];
  s2 = r2[0] + r2[1] + r2[2] + r2[3];
  float mean = s1 * (1.0f / Dd);
  float var = s2 * (1.0f / Dd) - mean * mean;
  float rstd = rsqrtf(var + 1e-3f);
  float4 gg = ((const float4*)g)[t];
  float4 bb = ((const float4*)bia)[t];
  ushort4 o;
  o.x = f2bf((v.x - mean) * rstd * gg.x + bb.x);
  o.y = f2bf((v.y - mean) * rstd * gg.y + bb.y);
  o.z = f2bf((v.z - mean) * rstd * gg.z + bb.z);
  o.w = f2bf((v.w - mean) * rstd * gg.w + bb.w);
  *((ushort4*)(out + (long)row * Dd + t * 4)) = o;
}

// ---------------- split heads / concat past / present ----------------
__global__ __launch_bounds__(256) void split_kernel(const unsigned short* __restrict__ c,
                                                    const float* __restrict__ past,
                                                    unsigned short* __restrict__ q,
                                                    unsigned short* __restrict__ kc_,
                                                    unsigned short* __restrict__ vc_,
                                                    float* __restrict__ present) {
  long idx = (long)blockIdx.x * 256 + threadIdx.x;
  int dh = idx & 63;
  int s = (int)((idx >> 6) & 2047);
  int h = (int)((idx >> 17) & 15);
  int b = (int)(idx >> 21);
  long crow = ((long)(b * Ss + s)) * (3 * Dd);
  int hd = h * DHh + dh;
  unsigned short qv = c[crow + hd];
  unsigned short kv = c[crow + Dd + hd];
  unsigned short vv = c[crow + 2 * Dd + hd];
  long bh = (long)b * Hh + h;
  q[(bh * Ss + s) * DHh + dh] = qv;
  kc_[(bh * NS + Pp + s) * DHh + dh] = kv;
  vc_[(bh * NS + Pp + s) * DHh + dh] = vv;
  present[((((long)b * 2 + 0) * Hh + h) * Ss + s) * DHh + dh] = bf2f(kv);
  present[((((long)b * 2 + 1) * Hh + h) * Ss + s) * DHh + dh] = bf2f(vv);
  if (s < Pp) {
    int p = s;
    float pk = past[((((long)b * 2 + 0) * Hh + h) * Pp + p) * DHh + dh];
    float pv = past[((((long)b * 2 + 1) * Hh + h) * Pp + p) * DHh + dh];
    kc_[(bh * NS + p) * DHh + dh] = f2bf(pk);
    vc_[(bh * NS + p) * DHh + dh] = f2bf(pv);
  }
}

// ---------------- V transpose: (z, NS, 64) -> (z, 64, NS) ----------------
__global__ __launch_bounds__(256) void vtr_kernel(const unsigned short* __restrict__ vcat,
                                                  unsigned short* __restrict__ vT) {
  __shared__ unsigned short Tl[64 * 72];
  int z = blockIdx.y;
  int s0 = blockIdx.x * 64;
  int t = threadIdx.x;
#pragma unroll
  for (int it = 0; it < 2; it++) {
    int idx = t + it * 256, row = idx >> 3, c8 = (idx & 7) * 8;
    *(short8*)&Tl[row * 72 + c8] = *(const short8*)(vcat + ((long)z * NS + s0 + row) * 64 + c8);
  }
  __syncthreads();
#pragma unroll
  for (int it = 0; it < 2; it++) {
    int idx = t + it * 256, row = idx >> 3, c8 = (idx & 7) * 8;
    short8 g;
#pragma unroll
    for (int e = 0; e < 8; e++) g[e] = (short)Tl[(c8 + e) * 72 + row];
    *(short8*)(vT + ((long)z * 64 + row) * NS + s0 + c8) = g;
  }
}

// ---------------- fused attention (round-4 structure + lgkm barriers) ----------------
__global__ __launch_bounds__(256) void attn_kernel(const unsigned short* __restrict__ qg,
                                                   const unsigned short* __restrict__ kcat,
                                                   const unsigned short* __restrict__ vTg,
                                                   float* __restrict__ wg,
                                                   unsigned short* __restrict__ am) {
  __shared__ unsigned short KV[128 * 72];
  __shared__ unsigned short Pl[128 * 136];
  int wgs = (blockIdx.x & 7) * 64 + (blockIdx.x >> 3);
  int z = wgs >> 4;
  int bx = 15 - (wgs & 15);
  int q0 = bx * 128;
  int t = threadIdx.x, lane = t & 63, wid = t >> 6;
  int lr = lane & 15, kgp = lane >> 4;
  const unsigned short* qz = qg + (long)z * Ss * 64;
  const unsigned short* kz = kcat + (long)z * NS * 64;
  const unsigned short* vz = vTg + (long)z * 64 * NS;
  float* wz = wg + (long)z * Ss * NS;

  short8 qa[2][2];
#pragma unroll
  for (int i = 0; i < 2; i++)
#pragma unroll
    for (int kk = 0; kk < 2; kk++)
      qa[i][kk] =
          *(const short8*)(qz + (long)(q0 + wid * 32 + i * 16 + lr) * 64 + kk * 32 + kgp * 8);

  const int nt = bx + 2;
  float l_run[2][4] = {};

  for (int kt = 0; kt < nt; kt++) {
#pragma unroll
    for (int it = 0; it < 4; it++) {
      int idx = t + it * 256, row = idx >> 3, c8 = (idx & 7) * 8;
      *(short8*)&KV[row * 72 + c8] = *(const short8*)(kz + (long)(kt * 128 + row) * 64 + c8);
    }
    SYNC_LDS();
    floatx4 acc[2][8] = {};
    __builtin_amdgcn_s_setprio(1);
#pragma unroll
    for (int j = 0; j < 8; j++) {
      short8 b0 = *(const short8*)&KV[(j * 16 + lr) * 72 + kgp * 8];
      short8 b1 = *(const short8*)&KV[(j * 16 + lr) * 72 + 32 + kgp * 8];
#pragma unroll
      for (int i = 0; i < 2; i++) {
        acc[i][j] = __builtin_amdgcn_mfma_f32_16x16x32_bf16(qa[i][0], b0, acc[i][j], 0, 0, 0);
        acc[i][j] = __builtin_amdgcn_mfma_f32_16x16x32_bf16(qa[i][1], b1, acc[i][j], 0, 0, 0);
      }
    }
    __builtin_amdgcn_s_setprio(0);
#pragma unroll
    for (int i = 0; i < 2; i++) {
#pragma unroll
      for (int r = 0; r < 4; r++) {
        int row = q0 + wid * 32 + i * 16 + kgp * 4 + r;
        float su = 0.f;
#pragma unroll
        for (int j = 0; j < 8; j++) {
          int col = kt * 128 + j * 16 + lr;
          float e = (col > row + Pp) ? 0.f : __expf(acc[i][j][r] * 0.125f - 8.0f);
          su += e;
        }
        su += __shfl_xor(su, 1);
        su += __shfl_xor(su, 2);
        su += __shfl_xor(su, 4);
        su += __shfl_xor(su, 8);
        l_run[i][r] += su;
      }
    }
    SYNC_LDS();
  }

  float cc[2][4];
#pragma unroll
  for (int i = 0; i < 2; i++)
#pragma unroll
    for (int r = 0; r < 4; r++) cc[i][r] = 8.0f + __logf(l_run[i][r]);

  floatx4 oacc[2][4] = {};
  for (int kt = 0; kt < nt; kt++) {
#pragma unroll
    for (int it = 0; it < 4; it++) {
      int idx = t + it * 256, row = idx >> 3, c8 = (idx & 7) * 8;
      *(short8*)&KV[row * 72 + c8] = *(const short8*)(kz + (long)(kt * 128 + row) * 64 + c8);
    }
    SYNC_LDS();
    floatx4 acc[2][8] = {};
    __builtin_amdgcn_s_setprio(1);
#pragma unroll
    for (int j = 0; j < 8; j++) {
      short8 b0 = *(const short8*)&KV[(j * 16 + lr) * 72 + kgp * 8];
      short8 b1 = *(const short8*)&KV[(j * 16 + lr) * 72 + 32 + kgp * 8];
#pragma unroll
      for (int i = 0; i < 2; i++) {
        acc[i][j] = __builtin_amdgcn_mfma_f32_16x16x32_bf16(qa[i][0], b0, acc[i][j], 0, 0, 0);
        acc[i][j] = __builtin_amdgcn_mfma_f32_16x16x32_bf16(qa[i][1], b1, acc[i][j], 0, 0, 0);
      }
    }
    __builtin_amdgcn_s_setprio(0);
#pragma unroll
    for (int i = 0; i < 2; i++) {
#pragma unroll
      for (int r = 0; r < 4; r++) {
        int row = q0 + wid * 32 + i * 16 + kgp * 4 + r;
#pragma unroll
        for (int j = 0; j < 8; j++) {
          int col = kt * 128 + j * 16 + lr;
          float p = (col > row + Pp) ? 0.f : __expf(acc[i][j][r] * 0.125f - cc[i][r]);
          wz[(long)row * NS + col] = p;
          Pl[(wid * 32 + i * 16 + kgp * 4 + r) * 136 + j * 16 + lr] = f2bf(p);
        }
      }
    }
    SYNC_LDS();
#pragma unroll
    for (int it = 0; it < 4; it++) {
      int idx = t + it * 256, row = idx >> 4, c8 = (idx & 15) * 8;
      *(short8*)&KV[row * 136 + c8] = *(const short8*)(vz + (long)row * NS + kt * 128 + c8);
    }
    SYNC_LDS();
    __builtin_amdgcn_s_setprio(1);
#pragma unroll
    for (int kk = 0; kk < 4; kk++) {
      short8 pa[2];
#pragma unroll
      for (int i = 0; i < 2; i++)
        pa[i] = *(const short8*)&Pl[(wid * 32 + i * 16 + lr) * 136 + kk * 32 + kgp * 8];
#pragma unroll
      for (int jd = 0; jd < 4; jd++) {
        short8 bv = *(const short8*)&KV[(jd * 16 + lr) * 136 + kk * 32 + kgp * 8];
#pragma unroll
        for (int i = 0; i < 2; i++)
          oacc[i][jd] = __builtin_amdgcn_mfma_f32_16x16x32_bf16(pa[i], bv, oacc[i][jd], 0, 0, 0);
      }
    }
    __builtin_amdgcn_s_setprio(0);
    SYNC_LDS();
  }

  int zc0 = nt * 128;
  if (zc0 < NS) {
    for (int rr = 0; rr < 32; rr++) {
      int row = q0 + wid * 32 + rr;
      for (int c = zc0 + (lane << 2); c < NS; c += 256) {
        float4 z4 = {0.f, 0.f, 0.f, 0.f};
        *(float4*)&wz[(long)row * NS + c] = z4;
      }
    }
  }

#pragma unroll
  for (int i = 0; i < 2; i++)
#pragma unroll
    for (int jd = 0; jd < 4; jd++)
#pragma unroll
      for (int r = 0; r < 4; r++) {
        long row = (long)(z >> 4) * Ss + q0 + wid * 32 + i * 16 + kgp * 4 + r;
        int col = (z & 15) * 64 + jd * 16 + lr;
        am[row * Dd + col] = f2bf(oacc[i][jd][r]);
      }
}

// ------- bf16 MFMA GEMM: m97 staging + dbuf prefetch pipeline (T3-minimum) -------
enum { EPI_BF16_BIAS = 0, EPI_RES = 3, EPI_GELU = 4 };

template <int EPI, int NB>
__global__ __launch_bounds__(256) void gemm_k(const unsigned short* __restrict__ A16,
                                              const unsigned short* __restrict__ Bt,
                                              const float* __restrict__ bias,
                                              const float* __restrict__ res,
                                              void* __restrict__ outv,
                                              int M, int N, int K, int nwg) {
  constexpr int BM = 128, BN = 128;
  __shared__ unsigned short Alds[2][BM * 32];
  __shared__ unsigned short Blds[2][BN * 32];
  int cpx = nwg >> 3;
  int wgid = (blockIdx.x & 7) * cpx + (blockIdx.x >> 3);
  int mb = wgid / NB, nb = wgid % NB;
  int m0 = mb * BM, n0 = nb * BN;
  int t = threadIdx.x;
  int lane = t & 63, wid = t >> 6;
  int wm = wid >> 1, wn = wid & 1;
  floatx4 acc[4][4] = {};
  int lr = lane & 15, kg = lane >> 4;

  const unsigned short* Ab = A16 + (long)(m0 + wid * 32 + (lane >> 2)) * K + (lane & 3) * 8;
  const unsigned short* Bp = Bt + (long)(n0 + wid * 32 + (lane >> 2)) * K + (lane & 3) * 8;
  long rstride = (long)16 * K;
  int lds_w0 = (wid * 32) * 32, lds_w1 = (wid * 32 + 16) * 32;

#define STAGE(bb, k0)                              \
  do {                                             \
    gl_lds16(Ab + (k0), &Alds[bb][lds_w0]);        \
    gl_lds16(Ab + rstride + (k0), &Alds[bb][lds_w1]); \
    gl_lds16(Bp + (k0), &Blds[bb][lds_w0]);        \
    gl_lds16(Bp + rstride + (k0), &Blds[bb][lds_w1]); \
  } while (0)

  // prologue
  STAGE(0, 0);
  SYNC_VM();
  int cur = 0;
  int nt = K >> 5;
  for (int tt = 0; tt < nt; tt++) {
    if (tt + 1 < nt) STAGE(cur ^ 1, (tt + 1) * 32); // prefetch flies over compute
    short8 a[4], b[4];
#pragma unroll
    for (int i = 0; i < 4; i++)
      a[i] = *(const short8*)&Alds[cur][(wm * 64 + i * 16 + lr) * 32 + kg * 8];
#pragma unroll
    for (int j = 0; j < 4; j++)
      b[j] = *(const short8*)&Blds[cur][(wn * 64 + j * 16 + lr) * 32 + kg * 8];
    __builtin_amdgcn_s_setprio(1);
#pragma unroll
    for (int i = 0; i < 4; i++)
#pragma unroll
      for (int j = 0; j < 4; j++)
        acc[i][j] = __builtin_amdgcn_mfma_f32_16x16x32_bf16(a[i], b[j], acc[i][j], 0, 0, 0);
    __builtin_amdgcn_s_setprio(0);
    SYNC_VM(); // prefetch landed + all waves done reading cur
    cur ^= 1;
  }
#undef STAGE

#pragma unroll
  for (int i = 0; i < 4; i++) {
#pragma unroll
    for (int j = 0; j < 4; j++) {
#pragma unroll
      for (int r = 0; r < 4; r++) {
        int mm = m0 + wm * 64 + i * 16 + kg * 4 + r;
        int nn = n0 + wn * 64 + j * 16 + lr;
        float v = acc[i][j][r];
        if constexpr (EPI == EPI_BF16_BIAS) {
          ((unsigned short*)outv)[(long)mm * N + nn] = f2bf(v + bias[nn]);
        } else if constexpr (EPI == EPI_RES) {
          ((float*)outv)[(long)mm * N + nn] = v + bias[nn] + res[(long)mm * N + nn];
        } else if constexpr (EPI == EPI_GELU) {
          float xv = v + bias[nn];
          float u = xv + 0.044715f * xv * xv * xv;
          float tv = 1.0f - 2.0f / (__expf(1.5957691216057308f * u) + 1.0f);
          ((unsigned short*)outv)[(long)mm * N + nn] = f2bf(0.5f * xv * (1.0f + tv));
        }
      }
    }
  }
}

extern "C" void kernel_launch(void* const* d_in, const int* in_sizes, int n_in,
                              void* d_out, int out_size, void* d_ws, size_t ws_size,
                              hipStream_t stream) {
  (void)in_sizes; (void)n_in; (void)out_size; (void)ws_size;
  const float* x = (const float*)d_in[0];
  const float* past = (const float*)d_in[1];
  const float* qkv_w = (const float*)d_in[2];
  const float* qkv_b = (const float*)d_in[3];
  const float* merge_w = (const float*)d_in[4];
  const float* merge_b = (const float*)d_in[5];
  const float* ln1_w = (const float*)d_in[6];
  const float* ln1_b = (const float*)d_in[7];
  const float* ln2_w = (const float*)d_in[8];
  const float* ln2_b = (const float*)d_in[9];
  const float* g1 = (const float*)d_in[10];
  const float* b1 = (const float*)d_in[11];
  const float* g2 = (const float*)d_in[12];
  const float* b2 = (const float*)d_in[13];

  char* ws = (char*)d_ws;
  unsigned short* qkv_wT = (unsigned short*)(ws + 0);
  unsigned short* merge_wT = (unsigned short*)(ws + 6291456);
  unsigned short* ln1_wT = (unsigned short*)(ws + 8388608);
  unsigned short* ln2_wT = (unsigned short*)(ws + 16777216);
  unsigned short* h = (unsigned short*)(ws + 25165824);
  unsigned short* q = (unsigned short*)(ws + 33554432);
  unsigned short* kcat = (unsigned short*)(ws + 41943040);
  unsigned short* vcat = (unsigned short*)(ws + 50855936);
  unsigned short* c = (unsigned short*)(ws + 59768832);
  unsigned short* am = (unsigned short*)(ws + 59768832);  // reuse c after split
  unsigned short* vT = (unsigned short*)(ws + 68157440);  // in dead c tail during attn
  unsigned short* m1 = (unsigned short*)(ws + 25165824);  // reuse h..vcat after attn
  float* xa = (float*)(ws + 68157440);                    // vT dead by merge GEMM
  unsigned short* h2 = (unsigned short*)(ws + 84934656);

  float* xm_out = (float*)d_out;
  float* present = ((float*)d_out) + (long)Bb * Ss * Dd;
  float* w_out = present + (long)Bb * 2 * Hh * Ss * DHh;

  wt_cvt_kernel<<<dim3(3072 / 32, 1024 / 32), 256, 0, stream>>>(qkv_w, qkv_wT, 1024, 3072);
  wt_cvt_kernel<<<dim3(1024 / 32, 1024 / 32), 256, 0, stream>>>(merge_w, merge_wT, 1024, 1024);
  wt_cvt_kernel<<<dim3(4096 / 32, 1024 / 32), 256, 0, stream>>>(ln1_w, ln1_wT, 1024, 4096);
  wt_cvt_kernel<<<dim3(1024 / 32, 4096 / 32), 256, 0, stream>>>(ln2_w, ln2_wT, 4096, 1024);

  ln_kernel<<<Bb * Ss, 256, 0, stream>>>(x, g1, b1, h);

  gemm_k<EPI_BF16_BIAS, 24><<<32 * 24, 256, 0, stream>>>(
      h, qkv_wT, qkv_b, nullptr, c, 4096, 3072, 1024, 32 * 24);

  split_kernel<<<(Bb * Hh * Ss * DHh) / 256, 256, 0, stream>>>(c, past, q, kcat, vcat, present);

  vtr_kernel<<<dim3(NS / 64, Bb * Hh), 256, 0, stream>>>(vcat, vT);

  attn_kernel<<<512, 256, 0, stream>>>(q, kcat, vT, w_out, am);

  gemm_k<EPI_RES, 8><<<32 * 8, 256, 0, stream>>>(
      am, merge_wT, merge_b, x, xa, 4096, 1024, 1024, 32 * 8);

  ln_kernel<<<Bb * Ss, 256, 0, stream>>>(xa, g2, b2, h2);

  gemm_k<EPI_GELU, 32><<<32 * 32, 256, 0, stream>>>(
      h2, ln1_wT, ln1_b, nullptr, m1, 4096, 4096, 1024, 32 * 32);

  gemm_k<EPI_RES, 8><<<32 * 8, 256, 0, stream>>>(
      m1, ln2_wT, ln2_b, x, xm_out, 4096, 1024, 4096, 32 * 8);
}